// Round 1
// baseline (795.615 us; speedup 1.0000x reference)
//
#include <hip/hip_runtime.h>
#include <stdint.h>

// PQ soft-assignment layer, MI355X (gfx950).
// B=65536, feat=512, M=8, K=256, D=64.
// Strategy: per-wave 16 b-rows x one m. MFMA1 computes S^T = C*xhat^T so each
// lane holds a full 256-logit row -> in-register softmax (no LDS, no barriers).
// MFMA2 computes xhat^T = C^T * P^T with P relayout done via register shuffles.
// C is pre-converted to bf16 in d_ws in both [k][d] and [d][k] layouts so all
// MFMA fragment loads are contiguous 16B loads.

typedef float f32x4 __attribute__((ext_vector_type(4)));
typedef short s16x8 __attribute__((ext_vector_type(8)));
typedef unsigned short u16;

constexpr int MM = 8;     // groups
constexpr int KD = 256;   // codewords per group
constexpr int DD = 64;    // sub-dim

// float -> bf16 bits, round-to-nearest-even
__device__ __forceinline__ unsigned f2bf1(float f) {
  unsigned u = __float_as_uint(f);
  u += 0x7FFFu + ((u >> 16) & 1u);
  return u >> 16;
}
__device__ __forceinline__ unsigned packbf(float lo, float hi) {
  return f2bf1(lo) | (f2bf1(hi) << 16);
}

// Convert C (f32 [M][K][D]) into bf16 Cm [M][K][D] and CmT [M][D][K] in ws.
__global__ __launch_bounds__(256) void pq_prep(const float* __restrict__ C,
                                               u16* __restrict__ Cm,
                                               u16* __restrict__ Cmt) {
  int idx = blockIdx.x * 256 + threadIdx.x;
  if (idx >= MM * KD * DD) return;
  int d = idx & (DD - 1);
  int k = (idx >> 6) & (KD - 1);
  int m = idx >> 14;
  u16 v = (u16)f2bf1(C[idx]);
  Cm[idx] = v;
  Cmt[(m * DD + d) * KD + k] = v;
}

__global__ __launch_bounds__(256) void pq_main(const float* __restrict__ x,
                                               const u16* __restrict__ Cm,
                                               const u16* __restrict__ Cmt,
                                               float* __restrict__ xhat,
                                               float* __restrict__ codes) {
  const int tid = threadIdx.x;
  const int lane = tid & 63;
  const int wave = tid >> 6;   // 0..3
  const int c = lane & 15;     // frag col / this lane's b-column
  const int g = lane >> 4;     // 0..3 lane group
  const int m = blockIdx.x & 7;
  const int b0 = (blockIdx.x >> 3) * 64;
  const int brow = b0 + wave * 16 + c;   // this lane's b row

  // ---------------- load x slice, L2-normalize, build xhat B-frags ----------
  // B-operand layout (16x16x32): col = lane&15 (=b), k(=d) = g*8 + i
  const float* xp = x + (size_t)brow * (MM * DD) + m * DD;
  f32x4 xv[4];
#pragma unroll
  for (int kf = 0; kf < 2; ++kf) {
    const f32x4* p = (const f32x4*)(xp + kf * 32 + g * 8);
    xv[kf * 2 + 0] = p[0];
    xv[kf * 2 + 1] = p[1];
  }
  float ssq = 0.f;
#pragma unroll
  for (int t = 0; t < 4; ++t)
    ssq += xv[t].x * xv[t].x + xv[t].y * xv[t].y + xv[t].z * xv[t].z + xv[t].w * xv[t].w;
  ssq += __shfl_xor(ssq, 16);
  ssq += __shfl_xor(ssq, 32);
  const float inv = 1.0f / fmaxf(sqrtf(ssq), 1e-12f);

  s16x8 bx[2];
#pragma unroll
  for (int kf = 0; kf < 2; ++kf) {
    union { s16x8 v; unsigned u[4]; } un;
#pragma unroll
    for (int t = 0; t < 2; ++t) {
      f32x4 q = xv[kf * 2 + t];
      un.u[t * 2 + 0] = packbf(q.x * inv, q.y * inv);
      un.u[t * 2 + 1] = packbf(q.z * inv, q.w * inv);
    }
    bx[kf] = un.v;
  }

  // ---------------- MFMA1: S^T[k][b] = sum_d C[k][d] * xhat[b][d] -----------
  // A-frag (C): row(=k within frag) = c, d = kf*32 + g*8 + i  -> contiguous.
  // acc[rf]: value = ips[b=brow][k = rf*16 + 4*g + reg]
  f32x4 acc[16];
#pragma unroll
  for (int rf = 0; rf < 16; ++rf) acc[rf] = (f32x4){0.f, 0.f, 0.f, 0.f};

  const u16* cmp = Cm + ((size_t)m * KD + c) * DD + g * 8;
#pragma unroll 4
  for (int rf = 0; rf < 16; ++rf) {
#pragma unroll
    for (int kf = 0; kf < 2; ++kf) {
      s16x8 A = *(const s16x8*)(cmp + rf * 16 * DD + kf * 32);
      acc[rf] = __builtin_amdgcn_mfma_f32_16x16x32_bf16(A, bx[kf], acc[rf], 0, 0, 0);
    }
  }

  // ---------------- softmax over k (fully lane-local + 2 shuffles) ----------
  float mx = -3.0e38f;
#pragma unroll
  for (int rf = 0; rf < 16; ++rf)
    mx = fmaxf(mx, fmaxf(fmaxf(acc[rf].x, acc[rf].y), fmaxf(acc[rf].z, acc[rf].w)));
  mx = fmaxf(mx, __shfl_xor(mx, 16));
  mx = fmaxf(mx, __shfl_xor(mx, 32));

  float sum = 0.f;
#pragma unroll
  for (int rf = 0; rf < 16; ++rf) {
    acc[rf].x = __expf(acc[rf].x - mx);
    acc[rf].y = __expf(acc[rf].y - mx);
    acc[rf].z = __expf(acc[rf].z - mx);
    acc[rf].w = __expf(acc[rf].w - mx);
    sum += acc[rf].x + acc[rf].y + acc[rf].z + acc[rf].w;
  }
  sum += __shfl_xor(sum, 16);
  sum += __shfl_xor(sum, 32);
  const float rs = 1.0f / sum;
#pragma unroll
  for (int rf = 0; rf < 16; ++rf) {
    acc[rf].x *= rs; acc[rf].y *= rs; acc[rf].z *= rs; acc[rf].w *= rs;
  }

  // ---------------- store codes (f32, float4 per frag) ----------------------
  // acc[rf] = p[k = rf*16 + 4g .. +3] for row brow -> contiguous float4.
  float* cp = codes + ((size_t)brow * MM + m) * KD + 4 * g;
#pragma unroll
  for (int rf = 0; rf < 16; ++rf)
    *(f32x4*)(cp + rf * 16) = acc[rf];

  // ---------------- build P^T B-frags via register shuffles -----------------
  // Need B[k][col=b]: lane (c,g) holds k = kf*32 + 8g + i for its own b(=c col).
  // Source regs hold k = rf*16 + 4*g_src + r. For target (c,g):
  //   elems 0..3 from lane (c, 2*(g&1)), elems 4..7 from lane (c, 2*(g&1)+1),
  //   rf = 2*kf + (g>>1).
  unsigned w0[16], w1[16];
#pragma unroll
  for (int rf = 0; rf < 16; ++rf) {
    w0[rf] = packbf(acc[rf].x, acc[rf].y);
    w1[rf] = packbf(acc[rf].z, acc[rf].w);
  }
  const int laneA = c + 32 * (g & 1);
  const int laneB = laneA + 16;
  const bool hi = (g >> 1) != 0;
  s16x8 Bp[8];
#pragma unroll
  for (int kf = 0; kf < 8; ++kf) {
    unsigned a0e = __shfl(w0[2 * kf], laneA);
    unsigned a1e = __shfl(w1[2 * kf], laneA);
    unsigned a0o = __shfl(w0[2 * kf + 1], laneA);
    unsigned a1o = __shfl(w1[2 * kf + 1], laneA);
    unsigned b0e = __shfl(w0[2 * kf], laneB);
    unsigned b1e = __shfl(w1[2 * kf], laneB);
    unsigned b0o = __shfl(w0[2 * kf + 1], laneB);
    unsigned b1o = __shfl(w1[2 * kf + 1], laneB);
    union { s16x8 v; unsigned u[4]; } un;
    un.u[0] = hi ? a0o : a0e;
    un.u[1] = hi ? a1o : a1e;
    un.u[2] = hi ? b0o : b0e;
    un.u[3] = hi ? b1o : b1e;
    Bp[kf] = un.v;
  }

  // ---------------- MFMA2: xhat^T[d][b] = sum_k C[k][d] * p[b][k] -----------
  // A-frag (C^T): row(=d) = c, k = kf*32 + g*8 + i -> contiguous in CmT.
  f32x4 acc2[4];
#pragma unroll
  for (int rf = 0; rf < 4; ++rf) acc2[rf] = (f32x4){0.f, 0.f, 0.f, 0.f};

  const u16* ctp = Cmt + ((size_t)m * DD + c) * KD + g * 8;
#pragma unroll 2
  for (int rf2 = 0; rf2 < 4; ++rf2) {
#pragma unroll
    for (int kf = 0; kf < 8; ++kf) {
      s16x8 A = *(const s16x8*)(ctp + rf2 * 16 * KD + kf * 32);
      acc2[rf2] = __builtin_amdgcn_mfma_f32_16x16x32_bf16(A, Bp[kf], acc2[rf2], 0, 0, 0);
    }
  }

  // ---------------- store x_hat (d = rf2*16 + 4g + reg -> float4) -----------
  float* xo = xhat + (size_t)brow * (MM * DD) + m * DD + 4 * g;
#pragma unroll
  for (int rf2 = 0; rf2 < 4; ++rf2)
    *(f32x4*)(xo + rf2 * 16) = acc2[rf2];
}

extern "C" void kernel_launch(void* const* d_in, const int* in_sizes, int n_in,
                              void* d_out, int out_size, void* d_ws, size_t ws_size,
                              hipStream_t stream) {
  const float* x = (const float*)d_in[0];
  const float* C = (const float*)d_in[1];
  const int B = in_sizes[0] / (MM * DD);   // 65536

  float* xhat = (float*)d_out;
  float* codes = (float*)d_out + (size_t)B * MM * DD;

  u16* Cm = (u16*)d_ws;
  u16* Cmt = Cm + MM * KD * DD;   // 512 KB total in ws

  pq_prep<<<(MM * KD * DD + 255) / 256, 256, 0, stream>>>(C, Cm, Cmt);
  pq_main<<<(B / 64) * MM, 256, 0, stream>>>(x, Cm, Cmt, xhat, codes);
}